// Round 13
// baseline (175.624 us; speedup 1.0000x reference)
//
#include <hip/hip_runtime.h>
#include <hip/hip_bf16.h>

// ---- static sizes (match reference) ----
#define BATCH   256
#define N_PER   64
#define NNODES  (BATCH * N_PER)        // 16384
#define HID     32
#define NF      6
#define OUTF    2
#define P_PER   (N_PER * (N_PER - 1))  // 4032
#define E_TOT   (BATCH * P_PER)        // 1032192

// output layout (f32 elements): out | H | edge_index[2,E] | edge_weight[E]
#define O_OUT 0
#define O_H   (NNODES * OUTF)           // 32768
#define O_EI  (O_H + NNODES * HID)      // 557056
#define O_EW  (O_EI + 2 * E_TOT)        // 2621440

__global__ __launch_bounds__(256) void ope_fused_kernel(
    const float* __restrict__ node_x,
    const float* __restrict__ h_in,
    const float* __restrict__ Wn,  const float* __restrict__ bn,
    const float* __restrict__ We1, const float* __restrict__ be1,
    const float* __restrict__ We2, const float* __restrict__ be2,
    const float* __restrict__ Wz,  const float* __restrict__ bz,
    const float* __restrict__ Wr,  const float* __restrict__ br,
    const float* __restrict__ Wh,  const float* __restrict__ bh,
    const float* __restrict__ Wf,  const float* __restrict__ bf,
    float* __restrict__ out)
{
    __shared__ float sWz[64 * HID], sWr[64 * HID], sWh[64 * HID];
    __shared__ float sWn[NF * HID];
    __shared__ float sbn[HID], sbz[HID], sbr[HID], sbh[HID];
    __shared__ float sWf[HID * OUTF], sbf[OUTF];
    __shared__ float sw[64];   // collapsed edge-MLP weight: u=sw[0:32], v=sw[32:64]
    __shared__ float sc;       // collapsed edge-MLP bias
    __shared__ float sx[N_PER * HID];
    __shared__ float sh[N_PER * HID];
    __shared__ float shr[N_PER * HID];
    __shared__ float sRH[N_PER * HID];
    __shared__ float sa[N_PER], sb[N_PER];

    const int t = threadIdx.x;
    const int g = blockIdx.x;

    // ---- load + fold weights (K=1 DConv: W[0,0] + W[1,0]) ----
    for (int i = t; i < 64 * HID; i += 256) {
        sWz[i] = Wz[i] + Wz[2048 + i];
        sWr[i] = Wr[i] + Wr[2048 + i];
        sWh[i] = Wh[i] + Wh[2048 + i];
    }
    if (t < NF * HID) sWn[t] = Wn[t];
    if (t < HID) { sbn[t] = bn[t]; sbz[t] = bz[t]; sbr[t] = br[t]; sbh[t] = bh[t]; }
    if (t < HID * OUTF) sWf[t] = Wf[t];
    if (t < OUTF) sbf[t] = bf[t];
    if (t < 64) {
        float s = 0.f;
        #pragma unroll
        for (int m = 0; m < 64; ++m) s += We1[t * 64 + m] * We2[m];
        sw[t] = s;
    } else if (t == 64) {
        float s = be2[0];
        #pragma unroll
        for (int m = 0; m < 64; ++m) s += be1[m] * We2[m];
        sc = s;
    }
    __syncthreads();

    const int k  = t & 31;   // hidden index
    const int nr = t >> 5;   // node row 0..7; thread covers nodes nr + 8q

    // ---- node embedding x = node_x @ Wn + bn ; stage h ----
    #pragma unroll
    for (int q = 0; q < 8; ++q) {
        const int n = nr + 8 * q;
        const float* nx = node_x + (size_t)(g * N_PER + n) * NF;
        float acc = sbn[k];
        #pragma unroll
        for (int f = 0; f < NF; ++f) acc += nx[f] * sWn[f * HID + k];
        sx[n * HID + k] = acc;
        sh[n * HID + k] = h_in[(size_t)(g * N_PER + n) * HID + k];
    }
    __syncthreads();

    // ---- gates Z, R ; stash h*R ; per-node a,b ----
    float zreg[8];
    #pragma unroll
    for (int q = 0; q < 8; ++q) {
        const int n = nr + 8 * q;
        float az = sbz[k], ar = sbr[k];
        #pragma unroll
        for (int d = 0; d < HID; ++d) {
            const float xv = sx[n * HID + d];
            const float hv = sh[n * HID + d];
            az += xv * sWz[d * HID + k] + hv * sWz[(HID + d) * HID + k];
            ar += xv * sWr[d * HID + k] + hv * sWr[(HID + d) * HID + k];
        }
        const float Z = 1.f / (1.f + expf(-az));
        const float R = 1.f / (1.f + expf(-ar));
        zreg[q] = Z;
        shr[n * HID + k] = sh[n * HID + k] * R;
    }
    if (t < N_PER) {
        float a = 0.f, bb = 0.f;
        #pragma unroll
        for (int d = 0; d < HID; ++d) {
            const float xv = sx[t * HID + d];
            a  += xv * sw[d];
            bb += xv * sw[HID + d];
        }
        sa[t] = a; sb[t] = bb;
    }
    __syncthreads();

    // ---- H_tilde, H ; write H ; stash relu(H) ----
    #pragma unroll
    for (int q = 0; q < 8; ++q) {
        const int n = nr + 8 * q;
        float ah = sbh[k];
        #pragma unroll
        for (int d = 0; d < HID; ++d) {
            ah += sx[n * HID + d] * sWh[d * HID + k]
                + shr[n * HID + d] * sWh[(HID + d) * HID + k];
        }
        const float Ht = tanhf(ah);
        const float Z  = zreg[q];
        const float Hv = Z * sh[n * HID + k] + (1.f - Z) * Ht;
        out[O_H + (size_t)(g * N_PER + n) * HID + k] = Hv;
        sRH[n * HID + k] = fmaxf(Hv, 0.f);
    }
    __syncthreads();

    // ---- output projection ----
    if (t < N_PER * OUTF) {
        const int n = t >> 1, oc = t & 1;
        float acc = sbf[oc];
        #pragma unroll
        for (int d = 0; d < HID; ++d) acc += sRH[n * HID + d] * sWf[d * OUTF + oc];
        out[O_OUT + (size_t)(g * N_PER + n) * OUTF + oc] = acc;
    }

    // ---- edges: weight = relu(a_i + b_j + c), plus index rows ----
    const float cc = sc;
    for (int p = t; p < P_PER; p += 256) {
        const int i = p / 63;
        const int r = p - i * 63;
        const int j = r + (r >= i ? 1 : 0);
        float w = sa[i] + sb[j] + cc;
        w = fmaxf(w, 0.f);
        const size_t e = (size_t)g * P_PER + p;
        out[O_EW + e]         = w;
        out[O_EI + e]         = (float)(g * N_PER + i);
        out[O_EI + E_TOT + e] = (float)(g * N_PER + j);
    }
}

extern "C" void kernel_launch(void* const* d_in, const int* in_sizes, int n_in,
                              void* d_out, int out_size, void* d_ws, size_t ws_size,
                              hipStream_t stream) {
    // FINAL EVIDENCE MODEL (rounds 1,7,8,11,12):
    //  - R12 NaN under bf16-input reads => inputs are FLOAT32 (f32-as-bf16
    //    garbage is the only NaN source; true-bf16 compute is NaN-free).
    //  - R11 page fault on alpha remap + R12 no-fault on dict half-size reads
    //    => pointers are DICT-ordered.
    //  - R7/R8 failed with fully-correct dict+f32 input reads => output side
    //    was wrong: harness reads d_out as FLOAT32. Smoking gun: absmax
    //    8832.099609375 = f32 bits 0x460A0330 = packed pair of my bf16
    //    writes, high half bf16(8832) = an edge_index value landing in the
    //    harness's f32 H-region at half-stride. Deterministic, bit-identical.
    //  => everything f32, dict order, f32 stores.
    ope_fused_kernel<<<dim3(BATCH), dim3(256), 0, stream>>>(
        (const float*)d_in[0],   // node_x
        (const float*)d_in[2],   // h
        (const float*)d_in[3],   // Wn
        (const float*)d_in[4],   // bn
        (const float*)d_in[5],   // We1
        (const float*)d_in[6],   // be1
        (const float*)d_in[7],   // We2
        (const float*)d_in[8],   // be2
        (const float*)d_in[9],   // Wz
        (const float*)d_in[10],  // bz
        (const float*)d_in[11],  // Wr
        (const float*)d_in[12],  // br
        (const float*)d_in[13],  // Wh
        (const float*)d_in[14],  // bh
        (const float*)d_in[15],  // Wf
        (const float*)d_in[16],  // bf
        (float*)d_out);
}

// Round 14
// 109.325 us; speedup vs baseline: 1.6064x; 1.6064x over previous
//
#include <hip/hip_runtime.h>
#include <hip/hip_bf16.h>

// ---- static sizes (match reference) ----
#define BATCH   256
#define N_PER   64
#define NNODES  (BATCH * N_PER)        // 16384
#define HID     32
#define NF      6
#define OUTF    2
#define P_PER   (N_PER * (N_PER - 1))  // 4032
#define E_TOT   (BATCH * P_PER)        // 1032192

// output layout (f32 elements): out | H | edge_index[2,E] | edge_weight[E]
#define O_OUT 0
#define O_H   (NNODES * OUTF)           // 32768
#define O_EI  (O_H + NNODES * HID)      // 557056
#define O_EW  (O_EI + 2 * E_TOT)        // 2621440

// ws layout: float2 ab[16384] (128KB) | float c
#define WS_C_IDX 32768

// ================= Kernel A: per-node GRU + projection + edge dots =========
__global__ __launch_bounds__(256, 4) void ope_nodes_kernel(
    const float* __restrict__ node_x,
    const float* __restrict__ h_in,
    const float* __restrict__ Wn,  const float* __restrict__ bn,
    const float* __restrict__ We1, const float* __restrict__ be1,
    const float* __restrict__ We2, const float* __restrict__ be2,
    const float* __restrict__ Wz,  const float* __restrict__ bz,
    const float* __restrict__ Wr,  const float* __restrict__ br,
    const float* __restrict__ Wh,  const float* __restrict__ bh,
    const float* __restrict__ Wf,  const float* __restrict__ bf,
    float* __restrict__ out, float2* __restrict__ wsab, float* __restrict__ wsc)
{
    __shared__ float sWz[64 * HID], sWr[64 * HID], sWh[64 * HID];
    __shared__ float sWn[NF * HID];
    __shared__ float sbn[HID], sbz[HID], sbr[HID], sbh[HID];
    __shared__ float sWf[HID * OUTF], sbf[OUTF];
    __shared__ float sw[64];             // collapsed edge weights u|v
    __shared__ float sx[N_PER * HID];    // x
    __shared__ float sh[N_PER * HID];    // h
    __shared__ float shr[N_PER * HID];   // h*R
    __shared__ float sRH[N_PER * HID];   // relu(H)
    __shared__ float sa[N_PER], sb[N_PER];

    const int t = threadIdx.x;
    const int g = blockIdx.x;

    // ---- phase 1: stage + fold weights ----
    for (int i = t; i < 64 * HID; i += 256) {
        sWz[i] = Wz[i] + Wz[2048 + i];
        sWr[i] = Wr[i] + Wr[2048 + i];
        sWh[i] = Wh[i] + Wh[2048 + i];
    }
    if (t < NF * HID) sWn[t] = Wn[t];
    if (t < HID) { sbn[t] = bn[t]; sbz[t] = bz[t]; sbr[t] = br[t]; sbh[t] = bh[t]; }
    if (t < HID * OUTF) sWf[t] = Wf[t];
    if (t < OUTF) sbf[t] = bf[t];
    if (t < 64) {            // collapsed edge MLP weight
        float s = 0.f;
        for (int m = 0; m < 64; ++m) s += We1[t * 64 + m] * We2[m];
        sw[t] = s;
    } else if (t == 64) {    // collapsed edge bias -> ws (same value, all blocks)
        float s = be2[0];
        for (int m = 0; m < 64; ++m) s += be1[m] * We2[m];
        wsc[WS_C_IDX] = s;
    }
    __syncthreads();

    const int k  = t & 31;   // hidden index
    const int nr = t >> 5;   // node row 0..7 (thread's nodes: nr + 8q)

    // ---- phase 2: x = node_x@Wn + bn ; stage h ----
    for (int q = 0; q < 8; ++q) {
        const int n = nr + 8 * q;
        const float* nx = node_x + (size_t)(g * N_PER + n) * NF;
        float acc = sbn[k];
        #pragma unroll
        for (int f = 0; f < NF; ++f) acc += nx[f] * sWn[f * HID + k];
        sx[n * HID + k] = acc;
        sh[n * HID + k] = h_in[(size_t)(g * N_PER + n) * HID + k];
    }
    __syncthreads();

    // ---- phase 3: gates (d-outer, low pressure) ----
    float az[8], ar[8];
    #pragma unroll
    for (int q = 0; q < 8; ++q) { az[q] = sbz[k]; ar[q] = sbr[k]; }
    for (int d = 0; d < HID; ++d) {
        const float wzx = sWz[d * HID + k], wzh = sWz[(HID + d) * HID + k];
        const float wrx = sWr[d * HID + k], wrh = sWr[(HID + d) * HID + k];
        #pragma unroll
        for (int q = 0; q < 8; ++q) {
            const int n = nr + 8 * q;
            const float xv = sx[n * HID + d];
            const float hv = sh[n * HID + d];
            az[q] += xv * wzx + hv * wzh;
            ar[q] += xv * wrx + hv * wrh;
        }
    }
    float zreg[8];
    #pragma unroll
    for (int q = 0; q < 8; ++q) {
        const int n = nr + 8 * q;
        const float Z = 1.f / (1.f + expf(-az[q]));
        const float R = 1.f / (1.f + expf(-ar[q]));
        zreg[q] = Z;
        shr[n * HID + k] = sh[n * HID + k] * R;
    }
    if (t < N_PER) {         // per-node edge dots a,b
        float a = 0.f, bb = 0.f;
        for (int d = 0; d < HID; ++d) {
            const float xv = sx[t * HID + d];
            a  += xv * sw[d];
            bb += xv * sw[HID + d];
        }
        sa[t] = a; sb[t] = bb;
    }
    __syncthreads();

    // ---- phase 4: H_tilde (d-outer), H, relu(H) ----
    float ah[8];
    #pragma unroll
    for (int q = 0; q < 8; ++q) ah[q] = sbh[k];
    for (int d = 0; d < HID; ++d) {
        const float whx = sWh[d * HID + k], whh = sWh[(HID + d) * HID + k];
        #pragma unroll
        for (int q = 0; q < 8; ++q) {
            const int n = nr + 8 * q;
            ah[q] += sx[n * HID + d] * whx + shr[n * HID + d] * whh;
        }
    }
    #pragma unroll
    for (int q = 0; q < 8; ++q) {
        const int n = nr + 8 * q;
        const float Ht = tanhf(ah[q]);
        const float Z  = zreg[q];
        const float Hv = Z * sh[n * HID + k] + (1.f - Z) * Ht;
        out[O_H + (size_t)(g * N_PER + n) * HID + k] = Hv;
        sRH[n * HID + k] = fmaxf(Hv, 0.f);
    }
    if (t < N_PER) wsab[g * N_PER + t] = make_float2(sa[t], sb[t]);
    __syncthreads();

    // ---- phase 5: out = relu(H)@Wf + bf ----
    if (t < N_PER * OUTF) {
        const int n = t >> 1, oc = t & 1;
        float acc = sbf[oc];
        for (int d = 0; d < HID; ++d) acc += sRH[n * HID + d] * sWf[d * OUTF + oc];
        out[O_OUT + (size_t)(g * N_PER + n) * OUTF + oc] = acc;
    }
}

// ================= Kernel B: edge streams (pure BW, float4) ================
__global__ __launch_bounds__(256, 4) void ope_edges_kernel(
    const float2* __restrict__ wsab, const float* __restrict__ wsc,
    float* __restrict__ out)
{
    __shared__ float2 sab[N_PER];
    const int t  = threadIdx.x;
    const int g  = blockIdx.x >> 2;        // graph
    const int q4 = blockIdx.x & 3;         // quarter: 1008 edges
    if (t < N_PER) sab[t] = wsab[g * N_PER + t];
    const float c = wsc[WS_C_IDX];
    __syncthreads();

    if (t >= 252) return;
    const int p0 = q4 * 1008 + t * 4;
    const float gb = (float)(g * N_PER);

    float4 w4, i4, j4;
    #pragma unroll
    for (int u = 0; u < 4; ++u) {
        const int p = p0 + u;
        const int i = (p * 16645) >> 20;   // exact floor(p/63) for p<4032
        const int r = p - i * 63;
        const int j = r + (r >= i ? 1 : 0);
        const float w = fmaxf(sab[i].x + sab[j].y + c, 0.f);
        (&w4.x)[u] = w;
        (&i4.x)[u] = gb + (float)i;
        (&j4.x)[u] = gb + (float)j;
    }
    const size_t e = (size_t)g * P_PER + p0;
    *(float4*)&out[O_EW + e]         = w4;
    *(float4*)&out[O_EI + e]         = i4;
    *(float4*)&out[O_EI + E_TOT + e] = j4;
}

// ================= Fallback: round-13 monolithic (proven-pass) =============
__global__ __launch_bounds__(256) void ope_fused_fallback(
    const float* __restrict__ node_x, const float* __restrict__ h_in,
    const float* __restrict__ Wn,  const float* __restrict__ bn,
    const float* __restrict__ We1, const float* __restrict__ be1,
    const float* __restrict__ We2, const float* __restrict__ be2,
    const float* __restrict__ Wz,  const float* __restrict__ bz,
    const float* __restrict__ Wr,  const float* __restrict__ br,
    const float* __restrict__ Wh,  const float* __restrict__ bh,
    const float* __restrict__ Wf,  const float* __restrict__ bf,
    float* __restrict__ out)
{
    __shared__ float sWz[64 * HID], sWr[64 * HID], sWh[64 * HID];
    __shared__ float sWn[NF * HID];
    __shared__ float sbn[HID], sbz[HID], sbr[HID], sbh[HID];
    __shared__ float sWf[HID * OUTF], sbf[OUTF];
    __shared__ float sw[64];
    __shared__ float sc;
    __shared__ float sx[N_PER * HID], sh[N_PER * HID], shr[N_PER * HID], sRH[N_PER * HID];
    __shared__ float sa[N_PER], sb[N_PER];
    const int t = threadIdx.x, g = blockIdx.x;
    for (int i = t; i < 64 * HID; i += 256) {
        sWz[i] = Wz[i] + Wz[2048 + i];
        sWr[i] = Wr[i] + Wr[2048 + i];
        sWh[i] = Wh[i] + Wh[2048 + i];
    }
    if (t < NF * HID) sWn[t] = Wn[t];
    if (t < HID) { sbn[t] = bn[t]; sbz[t] = bz[t]; sbr[t] = br[t]; sbh[t] = bh[t]; }
    if (t < HID * OUTF) sWf[t] = Wf[t];
    if (t < OUTF) sbf[t] = bf[t];
    if (t < 64) {
        float s = 0.f;
        for (int m = 0; m < 64; ++m) s += We1[t * 64 + m] * We2[m];
        sw[t] = s;
    } else if (t == 64) {
        float s = be2[0];
        for (int m = 0; m < 64; ++m) s += be1[m] * We2[m];
        sc = s;
    }
    __syncthreads();
    const int k = t & 31, nr = t >> 5;
    for (int q = 0; q < 8; ++q) {
        const int n = nr + 8 * q;
        const float* nx = node_x + (size_t)(g * N_PER + n) * NF;
        float acc = sbn[k];
        for (int f = 0; f < NF; ++f) acc += nx[f] * sWn[f * HID + k];
        sx[n * HID + k] = acc;
        sh[n * HID + k] = h_in[(size_t)(g * N_PER + n) * HID + k];
    }
    __syncthreads();
    float zreg[8];
    for (int q = 0; q < 8; ++q) {
        const int n = nr + 8 * q;
        float az = sbz[k], ar = sbr[k];
        for (int d = 0; d < HID; ++d) {
            const float xv = sx[n * HID + d], hv = sh[n * HID + d];
            az += xv * sWz[d * HID + k] + hv * sWz[(HID + d) * HID + k];
            ar += xv * sWr[d * HID + k] + hv * sWr[(HID + d) * HID + k];
        }
        const float Z = 1.f / (1.f + expf(-az));
        const float R = 1.f / (1.f + expf(-ar));
        zreg[q] = Z;
        shr[n * HID + k] = sh[n * HID + k] * R;
    }
    if (t < N_PER) {
        float a = 0.f, bb = 0.f;
        for (int d = 0; d < HID; ++d) { a += sx[t * HID + d] * sw[d]; bb += sx[t * HID + d] * sw[HID + d]; }
        sa[t] = a; sb[t] = bb;
    }
    __syncthreads();
    for (int q = 0; q < 8; ++q) {
        const int n = nr + 8 * q;
        float ahv = sbh[k];
        for (int d = 0; d < HID; ++d)
            ahv += sx[n * HID + d] * sWh[d * HID + k] + shr[n * HID + d] * sWh[(HID + d) * HID + k];
        const float Ht = tanhf(ahv);
        const float Z = zreg[q];
        const float Hv = Z * sh[n * HID + k] + (1.f - Z) * Ht;
        out[O_H + (size_t)(g * N_PER + n) * HID + k] = Hv;
        sRH[n * HID + k] = fmaxf(Hv, 0.f);
    }
    __syncthreads();
    if (t < N_PER * OUTF) {
        const int n = t >> 1, oc = t & 1;
        float acc = sbf[oc];
        for (int d = 0; d < HID; ++d) acc += sRH[n * HID + d] * sWf[d * OUTF + oc];
        out[O_OUT + (size_t)(g * N_PER + n) * OUTF + oc] = acc;
    }
    const float cc = sc;
    for (int p = t; p < P_PER; p += 256) {
        const int i = p / 63, r = p - i * 63, j = r + (r >= i ? 1 : 0);
        const float w = fmaxf(sa[i] + sb[j] + cc, 0.f);
        const size_t e = (size_t)g * P_PER + p;
        out[O_EW + e] = w;
        out[O_EI + e] = (float)(g * N_PER + i);
        out[O_EI + E_TOT + e] = (float)(g * N_PER + j);
    }
}

extern "C" void kernel_launch(void* const* d_in, const int* in_sizes, int n_in,
                              void* d_out, int out_size, void* d_ws, size_t ws_size,
                              hipStream_t stream) {
    // f32 everywhere, dict pointer order (established rounds 1-13).
    const float* node_x = (const float*)d_in[0];
    const float* h   = (const float*)d_in[2];
    const float* Wn  = (const float*)d_in[3];
    const float* bn  = (const float*)d_in[4];
    const float* We1 = (const float*)d_in[5];
    const float* be1 = (const float*)d_in[6];
    const float* We2 = (const float*)d_in[7];
    const float* be2 = (const float*)d_in[8];
    const float* Wz  = (const float*)d_in[9];
    const float* bz  = (const float*)d_in[10];
    const float* Wr  = (const float*)d_in[11];
    const float* br  = (const float*)d_in[12];
    const float* Wh  = (const float*)d_in[13];
    const float* bh  = (const float*)d_in[14];
    const float* Wf  = (const float*)d_in[15];
    const float* bf  = (const float*)d_in[16];

    if (ws_size >= (size_t)(WS_C_IDX + 1) * sizeof(float)) {
        ope_nodes_kernel<<<dim3(BATCH), dim3(256), 0, stream>>>(
            node_x, h, Wn, bn, We1, be1, We2, be2, Wz, bz, Wr, br, Wh, bh, Wf, bf,
            (float*)d_out, (float2*)d_ws, (float*)d_ws);
        ope_edges_kernel<<<dim3(BATCH * 4), dim3(256), 0, stream>>>(
            (const float2*)d_ws, (const float*)d_ws, (float*)d_out);
    } else {
        ope_fused_fallback<<<dim3(BATCH), dim3(256), 0, stream>>>(
            node_x, h, Wn, bn, We1, be1, We2, be2, Wz, bz, Wr, br, Wh, bh, Wf, bf,
            (float*)d_out);
    }
}